// Round 15
// baseline (187.445 us; speedup 1.0000x reference)
//
#include <hip/hip_runtime.h>
#include <hip/hip_bf16.h>

#define BB 2
#define SEQ 2048
#define NHEAD 8
#define HD 64
#define ATT_T 1e-4f
#define QSCALE 0.18033688011112042f  // 0.125 * log2(e): scores in log2 domain

typedef short s16x8 __attribute__((ext_vector_type(8)));
typedef float f32x16 __attribute__((ext_vector_type(16)));

#define MFMA32(a, b, c) __builtin_amdgcn_mfma_f32_32x32x16_bf16((a), (b), (c), 0, 0, 0)
#define EXP2(x) __builtin_amdgcn_exp2f(x)
#define SB0() __builtin_amdgcn_sched_barrier(0)
// s_waitcnt imm: vmcnt[3:0]=bits3:0, expcnt=bits6:4, lgkmcnt=bits11:8, vmcnt[5:4]=bits15:14
#define WAITVM0() __builtin_amdgcn_s_waitcnt(0x0F70)
#define WAITVM4() __builtin_amdgcn_s_waitcnt(0x0F74)
#define WAITVM6() __builtin_amdgcn_s_waitcnt(0x0F76)
#define WAITVM8() __builtin_amdgcn_s_waitcnt(0x0F78)

__device__ __forceinline__ unsigned short bfr(float x) {
  __hip_bfloat16 h = __float2bfloat16(x);
  return __builtin_bit_cast(unsigned short, h);
}
__device__ __forceinline__ unsigned int packbf(float a, float b) {
  return (unsigned int)bfr(a) | ((unsigned int)bfr(b) << 16);
}
// 1-op truncating bf16 pack of two fp32 (v_perm_b32)
__device__ __forceinline__ unsigned int permpack(float a, float b) {
  return __builtin_amdgcn_perm(__builtin_bit_cast(unsigned int, b),
                               __builtin_bit_cast(unsigned int, a), 0x07060302u);
}
__device__ __forceinline__ void async16(const void* g, void* l) {
  __builtin_amdgcn_global_load_lds(
      (const __attribute__((address_space(1))) unsigned int*)g,
      (__attribute__((address_space(3))) unsigned int*)l, 16, 0, 0);
}

// ---------------------------------------------------------------------------
// prep: fp32->bf16 convert of fr/dt (blocks 0..4095) + weight transpose-
// convert WT[n][k]=bf16(W[k][n]) for 4 matrices (blocks 4096..4351).
// ---------------------------------------------------------------------------
__global__ __launch_bounds__(256) void prep(const float* __restrict__ fr,
                                            const float* __restrict__ dt,
                                            const float* __restrict__ w0,
                                            const float* __restrict__ w1,
                                            const float* __restrict__ w2,
                                            const float* __restrict__ w3,
                                            unsigned short* __restrict__ frB,
                                            unsigned short* __restrict__ dtB,
                                            unsigned short* __restrict__ o0,
                                            unsigned short* __restrict__ o1,
                                            unsigned short* __restrict__ o2,
                                            unsigned short* __restrict__ o3) {
  __shared__ float tle[64][65];
  const int bid = blockIdx.x;
  if (bid < 4096) {
    const float* x = bid < 2048 ? fr : dt;
    unsigned short* y = bid < 2048 ? frB : dtB;
    size_t i = ((size_t)(bid & 2047) * 256 + threadIdx.x) * 4;
    float4 v = *(const float4*)(x + i);
    uint2 p;
    p.x = packbf(v.x, v.y);
    p.y = packbf(v.z, v.w);
    *(uint2*)(y + i) = p;
    return;
  }
  const int idx = bid - 4096;
  const int z = idx >> 6;
  const float* W = z == 0 ? w0 : z == 1 ? w1 : z == 2 ? w2 : w3;
  unsigned short* WT = z == 0 ? o0 : z == 1 ? o1 : z == 2 ? o2 : o3;
  const int r0 = ((idx >> 3) & 7) * 64, c0 = (idx & 7) * 64;
  const int tr = threadIdx.x >> 4;
  const int tc = threadIdx.x & 15;
  #pragma unroll
  for (int i = 0; i < 4; i++) {
    int r = tr + i * 16;
    float4 v = *(const float4*)(W + (size_t)(r0 + r) * 512 + c0 + tc * 4);
    tle[r][tc * 4 + 0] = v.x;
    tle[r][tc * 4 + 1] = v.y;
    tle[r][tc * 4 + 2] = v.z;
    tle[r][tc * 4 + 3] = v.w;
  }
  __syncthreads();
  #pragma unroll
  for (int i = 0; i < 4; i++) {
    int c = tr + i * 16;
    int rr = tc * 4;
    uint2 p;
    p.x = packbf(tle[rr + 0][c], tle[rr + 1][c]);
    p.y = packbf(tle[rr + 2][c], tle[rr + 3][c]);
    *(uint2*)(WT + (size_t)(c0 + c) * 512 + r0 + rr) = p;
  }
}

// ---------------------------------------------------------------------------
// Fused Q/K/V projection GEMM — BARRIER-FREE K-loop (attn-R10 pattern):
// wave-private staging arena, all fragments via global_load_lds(16B),
// double-buffered with explicit vmcnt(6) (never 0 until last window).
// Block 256 = 4 waves as 2x2; wave tile 32x64; BK=32, 16 windows.
// grid (4, 64, 3). Epilogue (2 barriers only) writes head-major layouts.
// z=0: Q scaled QSCALE; z=1: K; z=2: V^T.
// ---------------------------------------------------------------------------
__global__ __launch_bounds__(256) void gemm_qkv(const unsigned short* __restrict__ frB,
                                                const unsigned short* __restrict__ dtB,
                                                const unsigned short* __restrict__ WqT,
                                                const unsigned short* __restrict__ WkT,
                                                const unsigned short* __restrict__ WvT,
                                                unsigned short* __restrict__ Qp,
                                                unsigned short* __restrict__ Kp,
                                                unsigned short* __restrict__ VTp) {
  __shared__ __align__(16) unsigned short gar[4][6144];  // 48 KB: wave arenas (2 slots x A1024|B2048)
  const int tid = threadIdx.x, lane = tid & 63, w = tid >> 6;
  const int l31 = lane & 31, lh = lane >> 5;
  const int m0 = blockIdx.y * 64, n0 = blockIdx.x * 128;
  const int z = blockIdx.z;
  const unsigned short* A = z == 0 ? frB : dtB;
  const unsigned short* BT = z == 0 ? WqT : (z == 1 ? WkT : WvT);
  unsigned short* OP = z == 0 ? Qp : (z == 1 ? Kp : VTp);
  const float scale = z == 0 ? QSCALE : 1.0f;

  const int wm = (w & 1) * 32, wn = (w >> 1) * 64;

  auto stage = [&](int kt, int slot) {
    const int k0 = kt * 32;
    unsigned short* dst = &gar[w][slot * 3072];
    #pragma unroll
    for (int ks = 0; ks < 2; ks++)
      async16(A + (size_t)(m0 + wm + l31) * 512 + k0 + ks * 16 + lh * 8,
              dst + ks * 512);
    #pragma unroll
    for (int gn = 0; gn < 2; gn++)
      #pragma unroll
      for (int ks = 0; ks < 2; ks++)
        async16(BT + (size_t)(n0 + wn + gn * 32 + l31) * 512 + k0 + ks * 16 + lh * 8,
                dst + 1024 + gn * 1024 + ks * 512);
  };

  f32x16 acc[2];
  #pragma unroll
  for (int j = 0; j < 2; j++)
    #pragma unroll
    for (int r = 0; r < 16; r++) acc[j][r] = 0.f;

  stage(0, 0);
  for (int kt = 0; kt < 16; ++kt) {
    const int slot = kt & 1;
    if (kt + 1 < 16) { stage(kt + 1, slot ^ 1); WAITVM6(); } else { WAITVM0(); }
    SB0();
    const unsigned short* as = &gar[w][slot * 3072];
    const unsigned short* bs = as + 1024;
    #pragma unroll
    for (int ks = 0; ks < 2; ++ks) {
      s16x8 af = *(const s16x8*)(as + ks * 512 + lane * 8);
      s16x8 b0 = *(const s16x8*)(bs + ks * 512 + lane * 8);
      s16x8 b1 = *(const s16x8*)(bs + 1024 + ks * 512 + lane * 8);
      acc[0] = MFMA32(af, b0, acc[0]);
      acc[1] = MFMA32(af, b1, acc[1]);
    }
  }

  unsigned short* smem = &gar[0][0];
  const int bb = m0 >> 11, s0 = m0 & 2047;
  __syncthreads();  // all waves done with staging arenas
  if (z <= 1) {
    #pragma unroll
    for (int j = 0; j < 2; j++)
      #pragma unroll
      for (int r = 0; r < 16; r++) {
        int mm = wm + (r & 3) + 8 * (r >> 2) + 4 * lh;
        int nn = wn + j * 32 + l31;
        smem[mm * 136 + nn] = bfr(acc[j][r] * scale);
      }
    __syncthreads();
    #pragma unroll
    for (int it = 0; it < 4; ++it) {
      int c = tid + it * 256;
      int mm = c >> 4, seg = c & 15;
      uint4 vdat = *(const uint4*)(smem + mm * 136 + seg * 8);
      int n = n0 + seg * 8, h = n >> 6, d = n & 63;
      *(uint4*)(OP + ((size_t)((bb * NHEAD + h) * SEQ + s0 + mm)) * HD + d) = vdat;
    }
  } else {
    #pragma unroll
    for (int j = 0; j < 2; j++)
      #pragma unroll
      for (int r = 0; r < 16; r += 2) {
        int mm = wm + (r & 3) + 8 * (r >> 2) + 4 * lh;  // even
        int nn = wn + j * 32 + l31;
        *(unsigned int*)(smem + nn * 72 + mm) = packbf(acc[j][r], acc[j][r + 1]);
      }
    __syncthreads();
    #pragma unroll
    for (int it = 0; it < 4; ++it) {
      int c = tid + it * 256;
      int nn = c >> 3, seg = c & 7;
      uint4 vdat = *(const uint4*)(smem + nn * 72 + seg * 8);
      int n = n0 + nn, h = n >> 6, d = n & 63;
      *(uint4*)(OP + ((size_t)((bb * NHEAD + h) * HD + d)) * SEQ + s0 + seg * 8) = vdat;
    }
  }
}

// ---------------------------------------------------------------------------
// Final projection — BARRIER-FREE (zero __syncthreads): wave-private staging,
// vmcnt(4) pipelining, 32x32 per wave, direct fp32 epilogue.
// grid (8, 64) = 512 blocks.
// ---------------------------------------------------------------------------
__global__ __launch_bounds__(256) void gemm_out(const unsigned short* __restrict__ A,
                                                const unsigned short* __restrict__ BT,
                                                const float* __restrict__ bias,
                                                float* __restrict__ O) {
  __shared__ __align__(16) unsigned short gar[4][4096];  // 32 KB: 2 slots x (A1024|B1024)
  const int tid = threadIdx.x, lane = tid & 63, w = tid >> 6;
  const int l31 = lane & 31, lh = lane >> 5;
  const int m0 = blockIdx.y * 64, n0 = blockIdx.x * 64;
  const int wm = (w & 1) * 32, wn = (w >> 1) * 32;

  auto stage = [&](int kt, int slot) {
    const int k0 = kt * 32;
    unsigned short* dst = &gar[w][slot * 2048];
    #pragma unroll
    for (int ks = 0; ks < 2; ks++) {
      async16(A + (size_t)(m0 + wm + l31) * 512 + k0 + ks * 16 + lh * 8,
              dst + ks * 512);
      async16(BT + (size_t)(n0 + wn + l31) * 512 + k0 + ks * 16 + lh * 8,
              dst + 1024 + ks * 512);
    }
  };

  f32x16 acc;
  #pragma unroll
  for (int r = 0; r < 16; r++) acc[r] = 0.f;

  stage(0, 0);
  for (int kt = 0; kt < 16; ++kt) {
    const int slot = kt & 1;
    if (kt + 1 < 16) { stage(kt + 1, slot ^ 1); WAITVM4(); } else { WAITVM0(); }
    SB0();
    const unsigned short* as = &gar[w][slot * 2048];
    #pragma unroll
    for (int ks = 0; ks < 2; ++ks) {
      s16x8 af = *(const s16x8*)(as + ks * 512 + lane * 8);
      s16x8 bf = *(const s16x8*)(as + 1024 + ks * 512 + lane * 8);
      acc = MFMA32(af, bf, acc);
    }
  }

  float bv = bias[n0 + wn + l31];
  #pragma unroll
  for (int r = 0; r < 16; r++) {
    int mm = wm + (r & 3) + 8 * (r >> 2) + 4 * lh;
    O[(size_t)(m0 + mm) * 512 + n0 + wn + l31] = acc[r] + bv;
  }
}

// ---------------------------------------------------------------------------
// MFMA flash attention (R11/R14 verbatim) — barrier-free K-loop + cross-chunk
// software pipelining; P-pack via v_perm truncation; explicit vmcnt.
// Block = 256 thr = 4 waves; wave = all 64 q x private 512-key quarter.
// ---------------------------------------------------------------------------
__global__ __launch_bounds__(256, 2) void attn_mfma(const unsigned short* __restrict__ Q,
                                                    const unsigned short* __restrict__ K,
                                                    const unsigned short* __restrict__ VT,
                                                    unsigned short* __restrict__ O) {
  __shared__ __align__(16) unsigned short arena[4][8192];  // 16 KB per wave
  __shared__ float larr[4][64];
  __shared__ float warr[4][64];

  const int tid = threadIdx.x;
  const int lane = tid & 63;
  const int w = tid >> 6;          // wave id = key quarter
  const int l31 = lane & 31, lh = lane >> 5;

  // XCD swizzle: pin 2 bh per XCD
  const int bid = blockIdx.x;
  const int g = bid & 7, j = bid >> 3;
  const int bh = g * 2 + (j >> 5);
  const int qt = j & 31;

  const unsigned short* Qh = Q + (size_t)bh * SEQ * HD;
  const unsigned short* Kh = K + (size_t)bh * SEQ * HD;
  const unsigned short* VTh = VT + (size_t)bh * HD * SEQ;

  s16x8 qf[2][4];
  #pragma unroll
  for (int q2 = 0; q2 < 2; q2++)
    #pragma unroll
    for (int t = 0; t < 4; t++)
      qf[q2][t] = *(const s16x8*)(Qh + (size_t)(qt * 64 + q2 * 32 + l31) * HD + 16 * t + 8 * lh);

  unsigned short* kbuf = &arena[w][0];     // 2 x 2048 ushorts
  unsigned short* vbuf = &arena[w][4096];  // 2 x 2048 ushorts
  const int kbase = w * 512;

  auto stageK = [&](int c, int slot) {
    const unsigned short* base = Kh + (size_t)(kbase + c * 32 + l31) * HD + lh * 8;
    #pragma unroll
    for (int tt = 0; tt < 4; tt++)
      async16(base + tt * 16, kbuf + slot * 2048 + tt * 512);
  };
  auto stageV = [&](int c, int slot) {
    #pragma unroll
    for (int dh = 0; dh < 2; dh++)
      #pragma unroll
      for (int kc = 0; kc < 2; kc++)
        async16(VTh + (size_t)(dh * 32 + l31) * SEQ + kbase + c * 32 + kc * 16 + lh * 8,
                vbuf + slot * 2048 + (dh * 2 + kc) * 512);
  };

  // ---------------- sweep 1: per-q l = sum(exp2(s)), pipelined -----------
  float lsum[2] = {0.f, 0.f};
  f32x16 scp[2];

  auto accum_l = [&]() {
    #pragma unroll
    for (int q2 = 0; q2 < 2; q2++) {
      float s0 = 0.f, s1 = 0.f, s2 = 0.f, s3 = 0.f;
      #pragma unroll
      for (int r = 0; r < 4; r++) {
        s0 += EXP2(scp[q2][r]);
        s1 += EXP2(scp[q2][4 + r]);
        s2 += EXP2(scp[q2][8 + r]);
        s3 += EXP2(scp[q2][12 + r]);
      }
      lsum[q2] += (s0 + s1) + (s2 + s3);
    }
  };

  stageK(0, 0);
  for (int c = 0; c < 16; ++c) {
    const int slot = c & 1;
    if (c + 1 < 16) stageK(c + 1, slot ^ 1);
    if (c > 0) accum_l();
    if (c + 1 < 16) { WAITVM4(); } else { WAITVM0(); }
    SB0();
    s16x8 kf[4];
    #pragma unroll
    for (int tt = 0; tt < 4; tt++)
      kf[tt] = *(const s16x8*)(kbuf + slot * 2048 + tt * 512 + lane * 8);
    #pragma unroll
    for (int q2 = 0; q2 < 2; q2++) {
      f32x16 sc;
      #pragma unroll
      for (int r = 0; r < 16; r++) sc[r] = 0.f;
      #pragma unroll
      for (int tt = 0; tt < 4; tt++) sc = MFMA32(kf[tt], qf[q2][tt], sc);
      scp[q2] = sc;
    }
  }
  accum_l();
  #pragma unroll
  for (int q2 = 0; q2 < 2; q2++) lsum[q2] += __shfl_xor(lsum[q2], 32);
  if (lh == 0) { larr[w][l31] = lsum[0]; larr[w][32 + l31] = lsum[1]; }
  __syncthreads();
  float tl[2];
  #pragma unroll
  for (int q2 = 0; q2 < 2; q2++)
    tl[q2] = ATT_T * (larr[0][q2 * 32 + l31] + larr[1][q2 * 32 + l31] +
                      larr[2][q2 * 32 + l31] + larr[3][q2 * 32 + l31]);

  // ---------------- sweep 2: clip + PV, pipelined ----------------
  f32x16 acc[2][2];
  #pragma unroll
  for (int q2 = 0; q2 < 2; q2++)
    #pragma unroll
    for (int dh = 0; dh < 2; dh++)
      #pragma unroll
      for (int r = 0; r < 16; r++) acc[q2][dh][r] = 0.f;
  float wacc[2] = {0.f, 0.f};
  s16x8 vfp[2][2];

  auto softmax_pv = [&]() {
    s16x8 pf[2][2];
    #pragma unroll
    for (int q2 = 0; q2 < 2; q2++) {
      uint2 quads[4];
      #pragma unroll
      for (int gq = 0; gq < 4; gq++) {
        float u0 = fmaxf(EXP2(scp[q2][4 * gq + 0]) - tl[q2], 0.f);
        float u1 = fmaxf(EXP2(scp[q2][4 * gq + 1]) - tl[q2], 0.f);
        float u2 = fmaxf(EXP2(scp[q2][4 * gq + 2]) - tl[q2], 0.f);
        float u3 = fmaxf(EXP2(scp[q2][4 * gq + 3]) - tl[q2], 0.f);
        wacc[q2] += (u0 + u1) + (u2 + u3);
        quads[gq].x = permpack(u0, u1);
        quads[gq].y = permpack(u2, u3);
      }
      #pragma unroll
      for (int tp = 0; tp < 2; tp++) {
        uint2 ea, eb;
        ea.x = (unsigned)__shfl_xor((int)quads[2 * tp].x, 32);
        ea.y = (unsigned)__shfl_xor((int)quads[2 * tp].y, 32);
        eb.x = (unsigned)__shfl_xor((int)quads[2 * tp + 1].x, 32);
        eb.y = (unsigned)__shfl_xor((int)quads[2 * tp + 1].y, 32);
        uint4 fr;
        if (lh == 0) { fr.x = quads[2 * tp].x; fr.y = quads[2 * tp].y; fr.z = ea.x; fr.w = ea.y; }
        else         { fr.x = eb.x; fr.y = eb.y; fr.z = quads[2 * tp + 1].x; fr.w = quads[2 * tp + 1].y; }
        pf[q2][tp] = __builtin_bit_cast(s16x8, fr);
      }
    }
    #pragma unroll
    for (int q2 = 0; q2 < 2; q2++)
      #pragma unroll
      for (int dh = 0; dh < 2; dh++) {
        acc[q2][dh] = MFMA32(pf[q2][0], vfp[dh][0], acc[q2][dh]);
        acc[q2][dh] = MFMA32(pf[q2][1], vfp[dh][1], acc[q2][dh]);
      }
  };

  stageK(0, 0);
  stageV(0, 0);
  for (int c = 0; c < 16; ++c) {
    const int slot = c & 1;
    if (c + 1 < 16) { stageK(c + 1, slot ^ 1); stageV(c + 1, slot ^ 1); }
    if (c > 0) softmax_pv();
    if (c + 1 < 16) { WAITVM8(); } else { WAITVM0(); }
    SB0();
    s16x8 kf[4];
    #pragma unroll
    for (int tt = 0; tt < 4; tt++)
      kf[tt] = *(const s16x8*)(kbuf + slot * 2048 + tt * 512 + lane * 8);
    #pragma unroll
    for (int dh = 0; dh < 2; dh++)
      #pragma unroll
      for (int kc = 0; kc < 2; kc++)
        vfp[dh][kc] = *(const s16x8*)(vbuf + slot * 2048 + (dh * 2 + kc) * 512 + lane * 8);
    #pragma unroll
    for (int q2 = 0; q2 < 2; q2++) {
      f32x16 sc;
      #pragma unroll
      for (int r = 0; r < 16; r++) sc[r] = 0.f;
      #pragma unroll
      for (int tt = 0; tt < 4; tt++) sc = MFMA32(kf[tt], qf[q2][tt], sc);
      scp[q2] = sc;
    }
  }
  softmax_pv();

  // ---------------- cross-wave merge + output ----------------
  #pragma unroll
  for (int q2 = 0; q2 < 2; q2++) wacc[q2] += __shfl_xor(wacc[q2], 32);
  if (lh == 0) { warr[w][l31] = wacc[0]; warr[w][32 + l31] = wacc[1]; }
  __syncthreads();

  float* plane0 = (float*)&arena[0][0];
  float* plane1 = (float*)&arena[2][0];

  if (w >= 2) {
    float* pl = (w == 2) ? plane0 : plane1;
    #pragma unroll
    for (int q2 = 0; q2 < 2; q2++)
      #pragma unroll
      for (int dh = 0; dh < 2; dh++)
        #pragma unroll
        for (int r = 0; r < 16; r++) {
          int ql = q2 * 32 + (r & 3) + 8 * (r >> 2) + 4 * lh;
          pl[ql * 64 + dh * 32 + l31] = acc[q2][dh][r];
        }
  }
  __syncthreads();
  if (w < 2) {
    float* pl = (w == 0) ? plane0 : plane1;
    #pragma unroll
    for (int q2 = 0; q2 < 2; q2++)
      #pragma unroll
      for (int dh = 0; dh < 2; dh++)
        #pragma unroll
        for (int r = 0; r < 16; r++) {
          int ql = q2 * 32 + (r & 3) + 8 * (r >> 2) + 4 * lh;
          acc[q2][dh][r] += pl[ql * 64 + dh * 32 + l31];
        }
  }
  __syncthreads();
  if (w == 1) {
    #pragma unroll
    for (int q2 = 0; q2 < 2; q2++)
      #pragma unroll
      for (int dh = 0; dh < 2; dh++)
        #pragma unroll
        for (int r = 0; r < 16; r++) {
          int ql = q2 * 32 + (r & 3) + 8 * (r >> 2) + 4 * lh;
          plane0[ql * 64 + dh * 32 + l31] = acc[q2][dh][r];
        }
  }
  __syncthreads();
  unsigned short* otile = &arena[2][0];
  if (w == 0) {
    #pragma unroll
    for (int q2 = 0; q2 < 2; q2++)
      #pragma unroll
      for (int dh = 0; dh < 2; dh++)
        #pragma unroll
        for (int r = 0; r < 16; r++) {
          int ql = q2 * 32 + (r & 3) + 8 * (r >> 2) + 4 * lh;
          float wt = warr[0][ql] + warr[1][ql] + warr[2][ql] + warr[3][ql];
          float v = (acc[q2][dh][r] + plane0[ql * 64 + dh * 32 + l31]) / wt;
          otile[ql * 64 + dh * 32 + l31] = bfr(v);
        }
  }
  __syncthreads();
  const int b = bh >> 3, h = bh & 7;
  #pragma unroll
  for (int it = 0; it < 2; ++it) {
    int c2 = tid + it * 256;
    int mm = c2 >> 3, seg = c2 & 7;
    uint4 vdat = *(const uint4*)(otile + mm * 64 + seg * 8);
    *(uint4*)(O + ((size_t)(b * SEQ + qt * 64 + mm)) * 512 + h * HD + seg * 8) = vdat;
  }
}

// ---------------------------------------------------------------------------
extern "C" void kernel_launch(void* const* d_in, const int* in_sizes, int n_in,
                              void* d_out, int out_size, void* d_ws, size_t ws_size,
                              hipStream_t stream) {
  const float* fr = (const float*)d_in[0];
  const float* dt = (const float*)d_in[1];
  const float* Wq = (const float*)d_in[2];
  const float* Wk = (const float*)d_in[3];
  const float* Wv = (const float*)d_in[4];
  const float* Wo = (const float*)d_in[5];
  const float* bo = (const float*)d_in[6];
  float* out = (float*)d_out;

  const size_t planeE = (size_t)BB * SEQ * 512;  // 2,097,152 elements
  const size_t wE = 512 * 512;
  unsigned short* p = (unsigned short*)d_ws;
  unsigned short* frB = p; p += planeE;
  unsigned short* dtB = p; p += planeE;
  unsigned short* WqT = p; p += wE;
  unsigned short* WkT = p; p += wE;
  unsigned short* WvT = p; p += wE;
  unsigned short* WoT = p; p += wE;
  unsigned short* Qp  = p; p += planeE;
  unsigned short* Kp  = p; p += planeE;
  unsigned short* VTp = p; p += planeE;
  unsigned short* aoB = p; p += planeE;

  prep<<<4352, 256, 0, stream>>>(fr, dt, Wq, Wk, Wv, Wo, frB, dtB, WqT, WkT, WvT, WoT);

  gemm_qkv<<<dim3(4, 64, 3), 256, 0, stream>>>(frB, dtB, WqT, WkT, WvT, Qp, Kp, VTp);

  attn_mfma<<<BB * NHEAD * 32, 256, 0, stream>>>(Qp, Kp, VTp, aoB);

  gemm_out<<<dim3(8, 64), 256, 0, stream>>>(aoB, WoT, bo, out);
}

// Round 16
// 162.363 us; speedup vs baseline: 1.1545x; 1.1545x over previous
//
#include <hip/hip_runtime.h>
#include <hip/hip_bf16.h>

#define BB 2
#define SEQ 2048
#define NHEAD 8
#define HD 64
#define ATT_T 1e-4f
#define QSCALE 0.18033688011112042f  // 0.125 * log2(e): scores in log2 domain

typedef short s16x8 __attribute__((ext_vector_type(8)));
typedef float f32x16 __attribute__((ext_vector_type(16)));

#define MFMA32(a, b, c) __builtin_amdgcn_mfma_f32_32x32x16_bf16((a), (b), (c), 0, 0, 0)
#define EXP2(x) __builtin_amdgcn_exp2f(x)
#define SB0() __builtin_amdgcn_sched_barrier(0)
// s_waitcnt imm: vmcnt[3:0]=bits3:0, expcnt=bits6:4, lgkmcnt=bits11:8, vmcnt[5:4]=bits15:14
#define WAITVM0() __builtin_amdgcn_s_waitcnt(0x0F70)
#define WAITVM4() __builtin_amdgcn_s_waitcnt(0x0F74)
#define WAITVM8() __builtin_amdgcn_s_waitcnt(0x0F78)

__device__ __forceinline__ unsigned short bfr(float x) {
  __hip_bfloat16 h = __float2bfloat16(x);
  return __builtin_bit_cast(unsigned short, h);
}
__device__ __forceinline__ unsigned int packbf(float a, float b) {
  return (unsigned int)bfr(a) | ((unsigned int)bfr(b) << 16);
}
// 1-op truncating bf16 pack of two fp32 (v_perm_b32)
__device__ __forceinline__ unsigned int permpack(float a, float b) {
  return __builtin_amdgcn_perm(__builtin_bit_cast(unsigned int, b),
                               __builtin_bit_cast(unsigned int, a), 0x07060302u);
}
__device__ __forceinline__ void async16(const void* g, void* l) {
  __builtin_amdgcn_global_load_lds(
      (const __attribute__((address_space(1))) unsigned int*)g,
      (__attribute__((address_space(3))) unsigned int*)l, 16, 0, 0);
}

// ---------------------------------------------------------------------------
// Transpose-convert: WT[n][k] = bf16(W[k][n]), 512x512, 4 matrices batched.
// ---------------------------------------------------------------------------
__global__ __launch_bounds__(256) void convT(const float* __restrict__ w0,
                                             const float* __restrict__ w1,
                                             const float* __restrict__ w2,
                                             const float* __restrict__ w3,
                                             unsigned short* __restrict__ o0,
                                             unsigned short* __restrict__ o1,
                                             unsigned short* __restrict__ o2,
                                             unsigned short* __restrict__ o3) {
  __shared__ float tle[64][65];
  const float* W = blockIdx.z == 0 ? w0 : blockIdx.z == 1 ? w1 : blockIdx.z == 2 ? w2 : w3;
  unsigned short* WT = blockIdx.z == 0 ? o0 : blockIdx.z == 1 ? o1 : blockIdx.z == 2 ? o2 : o3;
  const int r0 = blockIdx.y * 64, c0 = blockIdx.x * 64;
  const int tr = threadIdx.x >> 4;
  const int tc = threadIdx.x & 15;
  #pragma unroll
  for (int i = 0; i < 4; i++) {
    int r = tr + i * 16;
    float4 v = *(const float4*)(W + (size_t)(r0 + r) * 512 + c0 + tc * 4);
    tle[r][tc * 4 + 0] = v.x;
    tle[r][tc * 4 + 1] = v.y;
    tle[r][tc * 4 + 2] = v.z;
    tle[r][tc * 4 + 3] = v.w;
  }
  __syncthreads();
  #pragma unroll
  for (int i = 0; i < 4; i++) {
    int c = tr + i * 16;
    int rr = tc * 4;
    uint2 p;
    p.x = packbf(tle[rr + 0][c], tle[rr + 1][c]);
    p.y = packbf(tle[rr + 2][c], tle[rr + 3][c]);
    *(uint2*)(WT + (size_t)(c0 + c) * 512 + r0 + rr) = p;
  }
}

// ---------------------------------------------------------------------------
// Fused Q/K/V projection GEMM, fp32 A (fr/dt) converted to bf16 in registers
// during LDS staging (ds_write frag order — element k of row m lives at
// g*2048 + (k/16)*512 + ((k>>3)&1)*256 + (m&31)*8 + (k&7)). B via
// global_load_lds. 64x128 tile, BK=64 dbuf, 4 waves. grid (4, 64, 3).
// z=0: Q -> [bh][s][64] scaled QSCALE; z=1: K -> [bh][s][64]; z=2: V^T.
// ---------------------------------------------------------------------------
__global__ __launch_bounds__(256) void gemm_qkv(const float* __restrict__ frF,
                                                const float* __restrict__ dtF,
                                                const unsigned short* __restrict__ WqT,
                                                const unsigned short* __restrict__ WkT,
                                                const unsigned short* __restrict__ WvT,
                                                unsigned short* __restrict__ Qp,
                                                unsigned short* __restrict__ Kp,
                                                unsigned short* __restrict__ VTp) {
  __shared__ __align__(16) unsigned short smem[24576];  // A 2x4096 | B 2x8192 (48 KB)
  unsigned short* Asm = smem;
  unsigned short* Bsm = smem + 8192;
  const int tid = threadIdx.x, lane = tid & 63, w = tid >> 6;
  const int l31 = lane & 31, lh = lane >> 5;
  const int m0 = blockIdx.y * 64, n0 = blockIdx.x * 128;
  const int z = blockIdx.z;
  const float* A = z == 0 ? frF : dtF;
  const unsigned short* BT = z == 0 ? WqT : (z == 1 ? WkT : WvT);
  unsigned short* OP = z == 0 ? Qp : (z == 1 ? Kp : VTp);
  const float scale = z == 0 ? QSCALE : 1.0f;

  // A staging: thread owns (row = tid>>2, 16-k seg = (tid&3)*16).
  // FRAG LAYOUT: k-halves (8 elems) of one 16-k run are 256 ushorts apart.
  const int arow = tid >> 2, aseg = tid & 3;
  const float* Ap = A + (size_t)(m0 + arow) * 512 + aseg * 16;
  const int aoff = (arow >> 5) * 2048 + aseg * 512 + (arow & 31) * 8;

  auto stageB = [&](int kt, int buf) {
    const int k0 = kt * 64;
    #pragma unroll
    for (int i = 0; i < 4; i++) {
      int r = w * 4 + i, gn = r >> 2, ks = r & 3;
      async16(BT + (size_t)(n0 + gn * 32 + l31) * 512 + k0 + ks * 16 + lh * 8,
              Bsm + buf * 8192 + r * 512);
    }
  };
  auto ldA = [&](int kt, float4* r4) {
    #pragma unroll
    for (int i = 0; i < 4; i++) r4[i] = *(const float4*)(Ap + kt * 64 + i * 4);
  };
  auto wrA = [&](int buf, const float4* r4) {
    uint4 w0v, w1v;
    w0v.x = packbf(r4[0].x, r4[0].y); w0v.y = packbf(r4[0].z, r4[0].w);
    w0v.z = packbf(r4[1].x, r4[1].y); w0v.w = packbf(r4[1].z, r4[1].w);
    w1v.x = packbf(r4[2].x, r4[2].y); w1v.y = packbf(r4[2].z, r4[2].w);
    w1v.z = packbf(r4[3].x, r4[3].y); w1v.w = packbf(r4[3].z, r4[3].w);
    *(uint4*)(Asm + buf * 4096 + aoff) = w0v;          // k-half 0 (kk 0..7)
    *(uint4*)(Asm + buf * 4096 + aoff + 256) = w1v;    // k-half 1 (kk 8..15)
  };

  f32x16 acc[2];
  #pragma unroll
  for (int j = 0; j < 2; j++)
    #pragma unroll
    for (int r = 0; r < 16; r++) acc[j][r] = 0.f;

  float4 areg[4];
  ldA(0, areg);
  stageB(0, 0);
  wrA(0, areg);
  ldA(1, areg);

  for (int kt = 0; kt < 8; ++kt) {
    __syncthreads();
    if (kt + 1 < 8) {
      const int nb = (kt + 1) & 1;
      stageB(kt + 1, nb);
      wrA(nb, areg);
      if (kt + 2 < 8) ldA(kt + 2, areg);
    }
    const int buf = kt & 1;
    const unsigned short* as = Asm + buf * 4096 + (w & 1) * 2048;
    const unsigned short* bs = Bsm + buf * 8192 + (w >> 1) * 4096;
    #pragma unroll
    for (int ks = 0; ks < 4; ++ks) {
      s16x8 af = *(const s16x8*)(as + ks * 512 + lane * 8);
      s16x8 b0 = *(const s16x8*)(bs + ks * 512 + lane * 8);
      s16x8 b1 = *(const s16x8*)(bs + 2048 + ks * 512 + lane * 8);
      acc[0] = MFMA32(af, b0, acc[0]);
      acc[1] = MFMA32(af, b1, acc[1]);
    }
  }

  const int wm = (w & 1) * 32, wn = (w >> 1) * 64;
  const int bb = m0 >> 11, s0 = m0 & 2047;
  __syncthreads();
  if (z <= 1) {
    #pragma unroll
    for (int j = 0; j < 2; j++)
      #pragma unroll
      for (int r = 0; r < 16; r++) {
        int mm = wm + (r & 3) + 8 * (r >> 2) + 4 * lh;
        int nn = wn + j * 32 + l31;
        smem[mm * 136 + nn] = bfr(acc[j][r] * scale);
      }
    __syncthreads();
    #pragma unroll
    for (int it = 0; it < 4; ++it) {
      int c = tid + it * 256;
      int mm = c >> 4, seg = c & 15;
      uint4 vdat = *(const uint4*)(smem + mm * 136 + seg * 8);
      int n = n0 + seg * 8, h = n >> 6, d = n & 63;
      *(uint4*)(OP + ((size_t)((bb * NHEAD + h) * SEQ + s0 + mm)) * HD + d) = vdat;
    }
  } else {
    #pragma unroll
    for (int j = 0; j < 2; j++)
      #pragma unroll
      for (int r = 0; r < 16; r += 2) {
        int mm = wm + (r & 3) + 8 * (r >> 2) + 4 * lh;  // even
        int nn = wn + j * 32 + l31;
        *(unsigned int*)(smem + nn * 72 + mm) = packbf(acc[j][r], acc[j][r + 1]);
      }
    __syncthreads();
    #pragma unroll
    for (int it = 0; it < 4; ++it) {
      int c = tid + it * 256;
      int nn = c >> 3, seg = c & 7;
      uint4 vdat = *(const uint4*)(smem + nn * 72 + seg * 8);
      int n = n0 + nn, h = n >> 6, d = n & 63;
      *(uint4*)(OP + ((size_t)((bb * NHEAD + h) * HD + d)) * SEQ + s0 + seg * 8) = vdat;
    }
  }
}

// ---------------------------------------------------------------------------
// Final projection: out[4096,512] = aoB @ WoT^T + bias, fp32 out.
// 64x64 tiles, grid (8,64) = 512 blocks = 2 blocks/CU.
// BK=64 dbuf, 4 waves as 2x2 of 32x32. LDS 32 KB.
// ---------------------------------------------------------------------------
__global__ __launch_bounds__(256) void gemm_out(const unsigned short* __restrict__ A,
                                                const unsigned short* __restrict__ BT,
                                                const float* __restrict__ bias,
                                                float* __restrict__ O) {
  __shared__ __align__(16) unsigned short smem[16384];  // A 2x4096 | B 2x4096
  unsigned short* Asm = smem;
  unsigned short* Bsm = smem + 8192;
  const int tid = threadIdx.x, lane = tid & 63, w = tid >> 6;
  const int l31 = lane & 31, lh = lane >> 5;
  const int m0 = blockIdx.y * 64, n0 = blockIdx.x * 64;

  auto stage = [&](int kt, int buf) {
    const int k0 = kt * 64;
    #pragma unroll
    for (int i = 0; i < 2; i++) {
      int r = w * 2 + i, g = r >> 2, ks = r & 3;
      async16(A + (size_t)(m0 + g * 32 + l31) * 512 + k0 + ks * 16 + lh * 8,
              Asm + buf * 4096 + r * 512);
      async16(BT + (size_t)(n0 + g * 32 + l31) * 512 + k0 + ks * 16 + lh * 8,
              Bsm + buf * 4096 + r * 512);
    }
  };

  f32x16 acc;
  #pragma unroll
  for (int r = 0; r < 16; r++) acc[r] = 0.f;

  stage(0, 0);
  for (int kt = 0; kt < 8; ++kt) {
    __syncthreads();
    if (kt + 1 < 8) stage(kt + 1, (kt + 1) & 1);
    const int buf = kt & 1;
    const unsigned short* as = Asm + buf * 4096 + (w & 1) * 2048;
    const unsigned short* bs = Bsm + buf * 4096 + (w >> 1) * 2048;
    #pragma unroll
    for (int ks = 0; ks < 4; ++ks) {
      s16x8 af = *(const s16x8*)(as + ks * 512 + lane * 8);
      s16x8 bf = *(const s16x8*)(bs + ks * 512 + lane * 8);
      acc = MFMA32(af, bf, acc);
    }
  }

  const int wm = (w & 1) * 32, wn = (w >> 1) * 32;
  float bv = bias[n0 + wn + l31];
  #pragma unroll
  for (int r = 0; r < 16; r++) {
    int mm = wm + (r & 3) + 8 * (r >> 2) + 4 * lh;
    O[(size_t)(m0 + mm) * 512 + n0 + wn + l31] = acc[r] + bv;
  }
}

// ---------------------------------------------------------------------------
// MFMA flash attention (R11/R14 verbatim) — barrier-free K-loop + cross-chunk
// software pipelining; P-pack via v_perm truncation; explicit vmcnt.
// Block = 256 thr = 4 waves; wave = all 64 q x private 512-key quarter.
// ---------------------------------------------------------------------------
__global__ __launch_bounds__(256, 2) void attn_mfma(const unsigned short* __restrict__ Q,
                                                    const unsigned short* __restrict__ K,
                                                    const unsigned short* __restrict__ VT,
                                                    unsigned short* __restrict__ O) {
  __shared__ __align__(16) unsigned short arena[4][8192];  // 16 KB per wave
  __shared__ float larr[4][64];
  __shared__ float warr[4][64];

  const int tid = threadIdx.x;
  const int lane = tid & 63;
  const int w = tid >> 6;          // wave id = key quarter
  const int l31 = lane & 31, lh = lane >> 5;

  // XCD swizzle: pin 2 bh per XCD
  const int bid = blockIdx.x;
  const int g = bid & 7, j = bid >> 3;
  const int bh = g * 2 + (j >> 5);
  const int qt = j & 31;

  const unsigned short* Qh = Q + (size_t)bh * SEQ * HD;
  const unsigned short* Kh = K + (size_t)bh * SEQ * HD;
  const unsigned short* VTh = VT + (size_t)bh * HD * SEQ;

  s16x8 qf[2][4];
  #pragma unroll
  for (int q2 = 0; q2 < 2; q2++)
    #pragma unroll
    for (int t = 0; t < 4; t++)
      qf[q2][t] = *(const s16x8*)(Qh + (size_t)(qt * 64 + q2 * 32 + l31) * HD + 16 * t + 8 * lh);

  unsigned short* kbuf = &arena[w][0];     // 2 x 2048 ushorts
  unsigned short* vbuf = &arena[w][4096];  // 2 x 2048 ushorts
  const int kbase = w * 512;

  auto stageK = [&](int c, int slot) {
    const unsigned short* base = Kh + (size_t)(kbase + c * 32 + l31) * HD + lh * 8;
    #pragma unroll
    for (int tt = 0; tt < 4; tt++)
      async16(base + tt * 16, kbuf + slot * 2048 + tt * 512);
  };
  auto stageV = [&](int c, int slot) {
    #pragma unroll
    for (int dh = 0; dh < 2; dh++)
      #pragma unroll
      for (int kc = 0; kc < 2; kc++)
        async16(VTh + (size_t)(dh * 32 + l31) * SEQ + kbase + c * 32 + kc * 16 + lh * 8,
                vbuf + slot * 2048 + (dh * 2 + kc) * 512);
  };

  // ---------------- sweep 1: per-q l = sum(exp2(s)), pipelined -----------
  float lsum[2] = {0.f, 0.f};
  f32x16 scp[2];

  auto accum_l = [&]() {
    #pragma unroll
    for (int q2 = 0; q2 < 2; q2++) {
      float s0 = 0.f, s1 = 0.f, s2 = 0.f, s3 = 0.f;
      #pragma unroll
      for (int r = 0; r < 4; r++) {
        s0 += EXP2(scp[q2][r]);
        s1 += EXP2(scp[q2][4 + r]);
        s2 += EXP2(scp[q2][8 + r]);
        s3 += EXP2(scp[q2][12 + r]);
      }
      lsum[q2] += (s0 + s1) + (s2 + s3);
    }
  };

  stageK(0, 0);
  for (int c = 0; c < 16; ++c) {
    const int slot = c & 1;
    if (c + 1 < 16) stageK(c + 1, slot ^ 1);
    if (c > 0) accum_l();
    if (c + 1 < 16) { WAITVM4(); } else { WAITVM0(); }
    SB0();
    s16x8 kf[4];
    #pragma unroll
    for (int tt = 0; tt < 4; tt++)
      kf[tt] = *(const s16x8*)(kbuf + slot * 2048 + tt * 512 + lane * 8);
    #pragma unroll
    for (int q2 = 0; q2 < 2; q2++) {
      f32x16 sc;
      #pragma unroll
      for (int r = 0; r < 16; r++) sc[r] = 0.f;
      #pragma unroll
      for (int tt = 0; tt < 4; tt++) sc = MFMA32(kf[tt], qf[q2][tt], sc);
      scp[q2] = sc;
    }
  }
  accum_l();
  #pragma unroll
  for (int q2 = 0; q2 < 2; q2++) lsum[q2] += __shfl_xor(lsum[q2], 32);
  if (lh == 0) { larr[w][l31] = lsum[0]; larr[w][32 + l31] = lsum[1]; }
  __syncthreads();
  float tl[2];
  #pragma unroll
  for (int q2 = 0; q2 < 2; q2++)
    tl[q2] = ATT_T * (larr[0][q2 * 32 + l31] + larr[1][q2 * 32 + l31] +
                      larr[2][q2 * 32 + l31] + larr[3][q2 * 32 + l31]);

  // ---------------- sweep 2: clip + PV, pipelined ----------------
  f32x16 acc[2][2];
  #pragma unroll
  for (int q2 = 0; q2 < 2; q2++)
    #pragma unroll
    for (int dh = 0; dh < 2; dh++)
      #pragma unroll
      for (int r = 0; r < 16; r++) acc[q2][dh][r] = 0.f;
  float wacc[2] = {0.f, 0.f};
  s16x8 vfp[2][2];

  auto softmax_pv = [&]() {
    s16x8 pf[2][2];
    #pragma unroll
    for (int q2 = 0; q2 < 2; q2++) {
      uint2 quads[4];
      #pragma unroll
      for (int gq = 0; gq < 4; gq++) {
        float u0 = fmaxf(EXP2(scp[q2][4 * gq + 0]) - tl[q2], 0.f);
        float u1 = fmaxf(EXP2(scp[q2][4 * gq + 1]) - tl[q2], 0.f);
        float u2 = fmaxf(EXP2(scp[q2][4 * gq + 2]) - tl[q2], 0.f);
        float u3 = fmaxf(EXP2(scp[q2][4 * gq + 3]) - tl[q2], 0.f);
        wacc[q2] += (u0 + u1) + (u2 + u3);
        quads[gq].x = permpack(u0, u1);
        quads[gq].y = permpack(u2, u3);
      }
      #pragma unroll
      for (int tp = 0; tp < 2; tp++) {
        uint2 ea, eb;
        ea.x = (unsigned)__shfl_xor((int)quads[2 * tp].x, 32);
        ea.y = (unsigned)__shfl_xor((int)quads[2 * tp].y, 32);
        eb.x = (unsigned)__shfl_xor((int)quads[2 * tp + 1].x, 32);
        eb.y = (unsigned)__shfl_xor((int)quads[2 * tp + 1].y, 32);
        uint4 fr;
        if (lh == 0) { fr.x = quads[2 * tp].x; fr.y = quads[2 * tp].y; fr.z = ea.x; fr.w = ea.y; }
        else         { fr.x = eb.x; fr.y = eb.y; fr.z = quads[2 * tp + 1].x; fr.w = quads[2 * tp + 1].y; }
        pf[q2][tp] = __builtin_bit_cast(s16x8, fr);
      }
    }
    #pragma unroll
    for (int q2 = 0; q2 < 2; q2++)
      #pragma unroll
      for (int dh = 0; dh < 2; dh++) {
        acc[q2][dh] = MFMA32(pf[q2][0], vfp[dh][0], acc[q2][dh]);
        acc[q2][dh] = MFMA32(pf[q2][1], vfp[dh][1], acc[q2][dh]);
      }
  };

  stageK(0, 0);
  stageV(0, 0);
  for (int c = 0; c < 16; ++c) {
    const int slot = c & 1;
    if (c + 1 < 16) { stageK(c + 1, slot ^ 1); stageV(c + 1, slot ^ 1); }
    if (c > 0) softmax_pv();
    if (c + 1 < 16) { WAITVM8(); } else { WAITVM0(); }
    SB0();
    s16x8 kf[4];
    #pragma unroll
    for (int tt = 0; tt < 4; tt++)
      kf[tt] = *(const s16x8*)(kbuf + slot * 2048 + tt * 512 + lane * 8);
    #pragma unroll
    for (int dh = 0; dh < 2; dh++)
      #pragma unroll
      for (int kc = 0; kc < 2; kc++)
        vfp[dh][kc] = *(const s16x8*)(vbuf + slot * 2048 + (dh * 2 + kc) * 512 + lane * 8);
    #pragma unroll
    for (int q2 = 0; q2 < 2; q2++) {
      f32x16 sc;
      #pragma unroll
      for (int r = 0; r < 16; r++) sc[r] = 0.f;
      #pragma unroll
      for (int tt = 0; tt < 4; tt++) sc = MFMA32(kf[tt], qf[q2][tt], sc);
      scp[q2] = sc;
    }
  }
  softmax_pv();

  // ---------------- cross-wave merge + output ----------------
  #pragma unroll
  for (int q2 = 0; q2 < 2; q2++) wacc[q2] += __shfl_xor(wacc[q2], 32);
  if (lh == 0) { warr[w][l31] = wacc[0]; warr[w][32 + l31] = wacc[1]; }
  __syncthreads();

  float* plane0 = (float*)&arena[0][0];
  float* plane1 = (float*)&arena[2][0];

  if (w >= 2) {
    float* pl = (w == 2) ? plane0 : plane1;
    #pragma unroll
    for (int q2 = 0; q2 < 2; q2++)
      #pragma unroll
      for (int dh = 0; dh < 2; dh++)
        #pragma unroll
        for (int r = 0; r < 16; r++) {
          int ql = q2 * 32 + (r & 3) + 8 * (r >> 2) + 4 * lh;
          pl[ql * 64 + dh * 32 + l31] = acc[q2][dh][r];
        }
  }
  __syncthreads();
  if (w < 2) {
    float* pl = (w == 0) ? plane0 : plane1;
    #pragma unroll
    for (int q2 = 0; q2 < 2; q2++)
      #pragma unroll
      for (int dh = 0; dh < 2; dh++)
        #pragma unroll
        for (int r = 0; r < 16; r++) {
          int ql = q2 * 32 + (r & 3) + 8 * (r >> 2) + 4 * lh;
          acc[q2][dh][r] += pl[ql * 64 + dh * 32 + l31];
        }
  }
  __syncthreads();
  if (w == 1) {
    #pragma unroll
    for (int q2 = 0; q2 < 2; q2++)
      #pragma unroll
      for (int dh = 0; dh < 2; dh++)
        #pragma unroll
        for (int r = 0; r < 16; r++) {
          int ql = q2 * 32 + (r & 3) + 8 * (r >> 2) + 4 * lh;
          plane0[ql * 64 + dh * 32 + l31] = acc[q2][dh][r];
        }
  }
  __syncthreads();
  unsigned short* otile = &arena[2][0];
  if (w == 0) {
    #pragma unroll
    for (int q2 = 0; q2 < 2; q2++)
      #pragma unroll
      for (int dh = 0; dh < 2; dh++)
        #pragma unroll
        for (int r = 0; r < 16; r++) {
          int ql = q2 * 32 + (r & 3) + 8 * (r >> 2) + 4 * lh;
          float wt = warr[0][ql] + warr[1][ql] + warr[2][ql] + warr[3][ql];
          float v = (acc[q2][dh][r] + plane0[ql * 64 + dh * 32 + l31]) / wt;
          otile[ql * 64 + dh * 32 + l31] = bfr(v);
        }
  }
  __syncthreads();
  const int b = bh >> 3, h = bh & 7;
  #pragma unroll
  for (int it = 0; it < 2; ++it) {
    int c2 = tid + it * 256;
    int mm = c2 >> 3, seg = c2 & 7;
    uint4 vdat = *(const uint4*)(otile + mm * 64 + seg * 8);
    *(uint4*)(O + ((size_t)(b * SEQ + qt * 64 + mm)) * 512 + h * HD + seg * 8) = vdat;
  }
}

// ---------------------------------------------------------------------------
extern "C" void kernel_launch(void* const* d_in, const int* in_sizes, int n_in,
                              void* d_out, int out_size, void* d_ws, size_t ws_size,
                              hipStream_t stream) {
  const float* fr = (const float*)d_in[0];
  const float* dt = (const float*)d_in[1];
  const float* Wq = (const float*)d_in[2];
  const float* Wk = (const float*)d_in[3];
  const float* Wv = (const float*)d_in[4];
  const float* Wo = (const float*)d_in[5];
  const float* bo = (const float*)d_in[6];
  float* out = (float*)d_out;

  const size_t planeE = (size_t)BB * SEQ * 512;  // 2,097,152 elements
  const size_t wE = 512 * 512;
  unsigned short* p = (unsigned short*)d_ws;
  unsigned short* WqT = p; p += wE;
  unsigned short* WkT = p; p += wE;
  unsigned short* WvT = p; p += wE;
  unsigned short* WoT = p; p += wE;
  unsigned short* Qp  = p; p += planeE;
  unsigned short* Kp  = p; p += planeE;
  unsigned short* VTp = p; p += planeE;
  unsigned short* aoB = p; p += planeE;

  convT<<<dim3(8, 8, 4), 256, 0, stream>>>(Wq, Wk, Wv, Wo, WqT, WkT, WvT, WoT);

  gemm_qkv<<<dim3(4, 64, 3), 256, 0, stream>>>(fr, dt, WqT, WkT, WvT, Qp, Kp, VTp);

  attn_mfma<<<BB * NHEAD * 32, 256, 0, stream>>>(Qp, Kp, VTp, aoB);

  gemm_out<<<dim3(8, 64), 256, 0, stream>>>(aoB, WoT, bo, out);
}